// Round 7
// baseline (485.416 us; speedup 1.0000x reference)
//
#include <hip/hip_runtime.h>
#include <hip/hip_bf16.h>

#define D_FEAT 256
#define NCHUNK 16          // 16 chunks x 16 feats
#define NODES_PER_BLOCK 32

typedef __attribute__((ext_vector_type(8))) __bf16 bf16x8;
typedef __attribute__((ext_vector_type(4))) __bf16 bf16x4;
typedef __attribute__((ext_vector_type(4))) float f32x4;
typedef __attribute__((ext_vector_type(2))) float f32x2;

// ---------------------------------------------------------------------------
// Kernel 0: Wt[n][k] = bf16(W[k][n])   (256x256, tiny)
// ---------------------------------------------------------------------------
__global__ __launch_bounds__(256) void cast_wt(
    const float* __restrict__ W, __bf16* __restrict__ Wt) {
  const int n = blockIdx.x;
  const int k = threadIdx.x;
  Wt[n * 256 + k] = (__bf16)W[k * 256 + n];
}

// ---------------------------------------------------------------------------
// Kernel 1: S_ck = bf16( X @ W ) in CHUNK-MAJOR layout: S_ck[c][node][f]
// (c = feat>>4). Tile BM=128, BN=128, BK=32; operands swapped so D reg-dim
// runs along n -> 4 consecutive feats per lane = one 8B store (same chunk).
// ---------------------------------------------------------------------------
#define APITCH 40  // bf16 elems per row (pad 32->40; 2-way LDS alias = free)

__global__ __launch_bounds__(256) void gemm_mfma(
    const float* __restrict__ X, const __bf16* __restrict__ Wt,
    __bf16* __restrict__ S, int M) {
  __shared__ __bf16 As[128 * APITCH];  // 10 KiB
  __shared__ __bf16 Bs[128 * APITCH];  // 10 KiB
  const int tid = threadIdx.x;
  const int wave = tid >> 6;
  const int lane = tid & 63;
  const int m0 = blockIdx.y * 128;
  const int n0 = blockIdx.x * 128;
  const size_t chstride = (size_t)M * 16;   // elems per chunk region

  f32x4 acc[2][8] = {};

  const int l15 = lane & 15;
  const int kh8 = (lane >> 4) * 8;

  const int r = tid >> 1;            // 0..127
  const int kh = (tid & 1) * 16;     // 0 or 16
  const int gr = m0 + r;
  const bool valid = gr < M;
  const float* xsrc = X + (size_t)(valid ? gr : 0) * D_FEAT + kh;

  float4 pre[4];
#pragma unroll
  for (int q = 0; q < 4; ++q)
    pre[q] = valid ? *reinterpret_cast<const float4*>(xsrc + q * 4)
                   : make_float4(0.f, 0.f, 0.f, 0.f);

  const int nr = tid >> 1;           // B staging: 0..127
  const int qb = (tid & 1) * 16;     // 0 or 16

  for (int k0 = 0; k0 < D_FEAT; k0 += 32) {
    const __bf16* wsrc = Wt + (size_t)(n0 + nr) * D_FEAT + k0 + qb;
    bf16x8 wb0 = *reinterpret_cast<const bf16x8*>(wsrc);
    bf16x8 wb1 = *reinterpret_cast<const bf16x8*>(wsrc + 8);

    bf16x8 a0, a1;
    a0[0] = (__bf16)pre[0].x; a0[1] = (__bf16)pre[0].y;
    a0[2] = (__bf16)pre[0].z; a0[3] = (__bf16)pre[0].w;
    a0[4] = (__bf16)pre[1].x; a0[5] = (__bf16)pre[1].y;
    a0[6] = (__bf16)pre[1].z; a0[7] = (__bf16)pre[1].w;
    a1[0] = (__bf16)pre[2].x; a1[1] = (__bf16)pre[2].y;
    a1[2] = (__bf16)pre[2].z; a1[3] = (__bf16)pre[2].w;
    a1[4] = (__bf16)pre[3].x; a1[5] = (__bf16)pre[3].y;
    a1[6] = (__bf16)pre[3].z; a1[7] = (__bf16)pre[3].w;
    *reinterpret_cast<bf16x8*>(&As[r * APITCH + kh]) = a0;
    *reinterpret_cast<bf16x8*>(&As[r * APITCH + kh + 8]) = a1;
    *reinterpret_cast<bf16x8*>(&Bs[nr * APITCH + qb]) = wb0;
    *reinterpret_cast<bf16x8*>(&Bs[nr * APITCH + qb + 8]) = wb1;

    const bool have = (k0 + 32) < D_FEAT;
    float4 nxt[4];
    if (have && valid) {
#pragma unroll
      for (int q = 0; q < 4; ++q)
        nxt[q] = *reinterpret_cast<const float4*>(xsrc + k0 + 32 + q * 4);
    }
    __syncthreads();

    bf16x8 a[2], b[8];
#pragma unroll
    for (int rg = 0; rg < 2; ++rg)
      a[rg] = *reinterpret_cast<const bf16x8*>(
          &As[(wave * 32 + rg * 16 + l15) * APITCH + kh8]);
#pragma unroll
    for (int cg = 0; cg < 8; ++cg)
      b[cg] = *reinterpret_cast<const bf16x8*>(
          &Bs[(cg * 16 + l15) * APITCH + kh8]);
    // Operands swapped: D n = (l>>4)*4 + reg, m = l&15.
#pragma unroll
    for (int rg = 0; rg < 2; ++rg)
#pragma unroll
      for (int cg = 0; cg < 8; ++cg)
        acc[rg][cg] = __builtin_amdgcn_mfma_f32_16x16x32_bf16(
            b[cg], a[rg], acc[rg][cg], 0, 0, 0);
    __syncthreads();

    if (have && valid) {
#pragma unroll
      for (int q = 0; q < 4; ++q) pre[q] = nxt[q];
    }
  }

  // epilogue: lane writes 4 consecutive feats (one chunk) as 8B bf16x4,
  // into chunk-major layout S[c][m][f&15]
#pragma unroll
  for (int rg = 0; rg < 2; ++rg) {
    const int m = m0 + wave * 32 + rg * 16 + l15;
    if (m < M) {
#pragma unroll
      for (int cg = 0; cg < 8; ++cg) {
        const int nb = n0 + cg * 16 + (lane >> 4) * 4;
        bf16x4 p;
#pragma unroll
        for (int rr = 0; rr < 4; ++rr) p[rr] = (__bf16)acc[rg][cg][rr];
        *reinterpret_cast<bf16x4*>(
            &S[(size_t)(nb >> 4) * chstride + (size_t)m * 16 + (nb & 15)]) = p;
      }
    }
  }
}

// ---------------------------------------------------------------------------
// Kernel 2: rowptr via binary search on sorted adj_row
// ---------------------------------------------------------------------------
__global__ __launch_bounds__(256) void build_rowptr(
    const int* __restrict__ rows, int E, int* __restrict__ ptr, int N) {
  const int n = blockIdx.x * blockDim.x + threadIdx.x;
  if (n > N) return;
  int lo = 0, hi = E;
  while (lo < hi) {
    const int mid = (lo + hi) >> 1;
    if (rows[mid] < n) lo = mid + 1; else hi = mid;
  }
  ptr[n] = lo;
}

// ---------------------------------------------------------------------------
// Kernel 2b: pk[e] = (col[e]<<15) | bf16_bits(val[e])  (val>=0, 15 bits)
// One 4B word per edge -> 16-pass edge re-stream costs 205MB not 410MB.
// ---------------------------------------------------------------------------
__global__ __launch_bounds__(256) void pack_edges(
    const int* __restrict__ col, const float* __restrict__ val,
    uint32_t* __restrict__ pk, int E) {
  const int e = blockIdx.x * 256 + threadIdx.x;
  if (e >= E) return;
  const uint32_t bits = __float_as_uint(val[e]);
  const uint32_t b = (bits + 0x7fffu + ((bits >> 16) & 1u)) >> 16;  // rne bf16
  pk[e] = ((uint32_t)col[e] << 15) | (b & 0x7fffu);
}

// ---------------------------------------------------------------------------
// Kernel 3: chunked spmm. Block handles (tile of 32 nodes) x (one 16-feat
// chunk). bid = phase*8*T + tile*8 + x ; chunk = phase*8 + x. With round-
// robin block->XCD dispatch, chunk x lives on XCD x: the 3.2MB chunk slice
// is L2-resident -> gathers become L2 hits instead of fabric traffic.
// Wave = 1 node: lane = (edge slot g 0..7) x (feat pair f 0..7, 4B gather).
// ---------------------------------------------------------------------------
__global__ __launch_bounds__(256) void spmm_chunked(
    const __bf16* __restrict__ Sck, const int* __restrict__ ptr,
    const uint32_t* __restrict__ pk, const float* __restrict__ bias,
    float* __restrict__ out, int N, int T) {
  const int bid = blockIdx.x;
  const int phase = bid / (8 * T);
  const int rem = bid - phase * 8 * T;
  const int tile = rem >> 3;
  const int x = rem & 7;
  const int chunk = phase * 8 + x;

  const size_t chstride = (size_t)N * 16;
  const char* Sb = (const char*)(Sck + (size_t)chunk * chstride);

  const int wave = threadIdx.x >> 6;
  const int lane = threadIdx.x & 63;
  const int g = lane >> 3;          // edge slot
  const int f = lane & 7;           // feat pair
  const uint32_t fb = (uint32_t)f * 4;

  const f32x2 bb = *reinterpret_cast<const f32x2*>(bias + chunk * 16 + f * 2);

  const int nbase = tile * NODES_PER_BLOCK + wave * 8;
#pragma unroll 1
  for (int i = 0; i < 8; ++i) {
    const int n = nbase + i;
    if (n >= N) continue;
    const int e0 = ptr[n];
    const int e1 = ptr[n + 1];
    const int elast = e1 - 1;
    const int esafe = elast < 0 ? 0 : elast;
    const int nit = (e1 - e0 + 7) >> 3;

    float a0 = 0.f, a1 = 0.f;
    int e = e0 + g;
#pragma unroll 2
    for (int b = 0; b < nit; ++b, e += 8) {
      const bool ok = e <= elast;
      const int ee = ok ? e : esafe;
      const uint32_t p = pk[ee];
      float v = __uint_as_float((p & 0x7fffu) << 16);   // bf16 val -> f32
      v = ok ? v : 0.f;
      const uint32_t off = (p >> 10) & 0xFFFFFFE0u;     // (p>>15)*32 bytes
      const uint32_t sp = *reinterpret_cast<const uint32_t*>(Sb + off + fb);
      a0 = fmaf(v, __uint_as_float(sp << 16), a0);
      a1 = fmaf(v, __uint_as_float(sp & 0xffff0000u), a1);
    }
    // reduce across the 8 edge slots (lane bits 3,4,5)
    a0 += __shfl_xor(a0, 8, 64);  a1 += __shfl_xor(a1, 8, 64);
    a0 += __shfl_xor(a0, 16, 64); a1 += __shfl_xor(a1, 16, 64);
    a0 += __shfl_xor(a0, 32, 64); a1 += __shfl_xor(a1, 32, 64);
    if (g == 0) {
      f32x2 o;
      o[0] = a0 + bb[0];
      o[1] = a1 + bb[1];
      __builtin_nontemporal_store(
          o, reinterpret_cast<f32x2*>(out + (size_t)n * D_FEAT + chunk * 16 + f * 2));
    }
  }
}

// ---------------------------------------------------------------------------
extern "C" void kernel_launch(void* const* d_in, const int* in_sizes, int n_in,
                              void* d_out, int out_size, void* d_ws, size_t ws_size,
                              hipStream_t stream) {
  const float* x       = (const float*)d_in[0];
  const int*   adj_row = (const int*)d_in[1];
  const int*   adj_col = (const int*)d_in[2];
  const float* adj_val = (const float*)d_in[3];
  const float* weight  = (const float*)d_in[4];
  const float* bias    = (const float*)d_in[5];
  float*       out     = (float*)d_out;

  const int N = in_sizes[0] / D_FEAT;   // 100000
  const int E = in_sizes[1];            // 3200000

  // ws layout: Wt bf16 [256*256] | S_ck bf16 [N*256] | rowptr int [N+2] | pk u32 [E]
  __bf16*   Wt      = (__bf16*)d_ws;
  __bf16*   support = Wt + 256 * 256;
  int*      rowptr  = (int*)(support + (size_t)N * D_FEAT);
  uint32_t* pk      = (uint32_t*)(rowptr + N + 2);

  cast_wt<<<256, 256, 0, stream>>>(weight, Wt);

  {
    dim3 grid(D_FEAT / 128, (N + 127) / 128);
    gemm_mfma<<<grid, 256, 0, stream>>>(x, Wt, support, N);
  }
  {
    const int blocks = (N + 1 + 255) / 256;
    build_rowptr<<<blocks, 256, 0, stream>>>(adj_row, E, rowptr, N);
  }
  {
    const int blocks = (E + 255) / 256;
    pack_edges<<<blocks, 256, 0, stream>>>(adj_col, adj_val, pk, E);
  }
  {
    const int T = (N + NODES_PER_BLOCK - 1) / NODES_PER_BLOCK;  // 3125
    const int blocks = 2 * 8 * T;                               // 50000
    spmm_chunked<<<blocks, 256, 0, stream>>>(support, rowptr, pk, bias,
                                             out, N, T);
  }
}

// Round 8
// 278.840 us; speedup vs baseline: 1.7408x; 1.7408x over previous
//
#include <hip/hip_runtime.h>
#include <hip/hip_bf16.h>

#define D_FEAT 256

typedef __attribute__((ext_vector_type(8))) __bf16 bf16x8;
typedef __attribute__((ext_vector_type(4))) __bf16 bf16x4;
typedef __attribute__((ext_vector_type(4))) float f32x4;

// ---------------------------------------------------------------------------
// Kernel A (fused prep): blocks [0,RB) build rowptr via binary search on the
// sorted adj_row; blocks [RB, RB+256) transpose-cast W -> Wt bf16.
// ---------------------------------------------------------------------------
__global__ __launch_bounds__(256) void prep(
    const int* __restrict__ rows, int E, int* __restrict__ ptr, int N,
    const float* __restrict__ W, __bf16* __restrict__ Wt, int RB) {
  const int b = blockIdx.x;
  if (b < RB) {
    const int n = b * 256 + threadIdx.x;
    if (n > N) return;
    int lo = 0, hi = E;
    while (lo < hi) {
      const int mid = (lo + hi) >> 1;
      if (rows[mid] < n) lo = mid + 1; else hi = mid;
    }
    ptr[n] = lo;
  } else {
    const int n = b - RB;          // 0..255
    const int k = threadIdx.x;     // 0..255
    Wt[n * 256 + k] = (__bf16)W[k * 256 + n];
  }
}

// ---------------------------------------------------------------------------
// Kernel 1: S = bf16( X @ W )  via mfma_f32_16x16x32_bf16
// Tile BM=128, BN=128, BK=32; operands SWAPPED (A=Wt rows, B=X rows) so the
// D reg-dim runs along n -> epilogue packs 4 consecutive bf16 per 8B store.
// ---------------------------------------------------------------------------
#define APITCH 40  // bf16 elems per row (pad 32->40; 2-way LDS alias = free)

__global__ __launch_bounds__(256) void gemm_mfma(
    const float* __restrict__ X, const __bf16* __restrict__ Wt,
    __bf16* __restrict__ S, int M) {
  __shared__ __bf16 As[128 * APITCH];  // 10 KiB
  __shared__ __bf16 Bs[128 * APITCH];  // 10 KiB
  const int tid = threadIdx.x;
  const int wave = tid >> 6;
  const int lane = tid & 63;
  const int m0 = blockIdx.y * 128;
  const int n0 = blockIdx.x * 128;

  f32x4 acc[2][8] = {};

  const int l15 = lane & 15;
  const int kh8 = (lane >> 4) * 8;

  const int r = tid >> 1;            // 0..127
  const int kh = (tid & 1) * 16;     // 0 or 16
  const int gr = m0 + r;
  const bool valid = gr < M;
  const float* xsrc = X + (size_t)(valid ? gr : 0) * D_FEAT + kh;

  float4 pre[4];
#pragma unroll
  for (int q = 0; q < 4; ++q)
    pre[q] = valid ? *reinterpret_cast<const float4*>(xsrc + q * 4)
                   : make_float4(0.f, 0.f, 0.f, 0.f);

  const int nr = tid >> 1;           // B staging: 0..127
  const int qb = (tid & 1) * 16;     // 0 or 16

  for (int k0 = 0; k0 < D_FEAT; k0 += 32) {
    const __bf16* wsrc = Wt + (size_t)(n0 + nr) * D_FEAT + k0 + qb;
    bf16x8 wb0 = *reinterpret_cast<const bf16x8*>(wsrc);
    bf16x8 wb1 = *reinterpret_cast<const bf16x8*>(wsrc + 8);

    bf16x8 a0, a1;
    a0[0] = (__bf16)pre[0].x; a0[1] = (__bf16)pre[0].y;
    a0[2] = (__bf16)pre[0].z; a0[3] = (__bf16)pre[0].w;
    a0[4] = (__bf16)pre[1].x; a0[5] = (__bf16)pre[1].y;
    a0[6] = (__bf16)pre[1].z; a0[7] = (__bf16)pre[1].w;
    a1[0] = (__bf16)pre[2].x; a1[1] = (__bf16)pre[2].y;
    a1[2] = (__bf16)pre[2].z; a1[3] = (__bf16)pre[2].w;
    a1[4] = (__bf16)pre[3].x; a1[5] = (__bf16)pre[3].y;
    a1[6] = (__bf16)pre[3].z; a1[7] = (__bf16)pre[3].w;
    *reinterpret_cast<bf16x8*>(&As[r * APITCH + kh]) = a0;
    *reinterpret_cast<bf16x8*>(&As[r * APITCH + kh + 8]) = a1;
    *reinterpret_cast<bf16x8*>(&Bs[nr * APITCH + qb]) = wb0;
    *reinterpret_cast<bf16x8*>(&Bs[nr * APITCH + qb + 8]) = wb1;

    const bool have = (k0 + 32) < D_FEAT;
    float4 nxt[4];
    if (have && valid) {
#pragma unroll
      for (int q = 0; q < 4; ++q)
        nxt[q] = *reinterpret_cast<const float4*>(xsrc + k0 + 32 + q * 4);
    }
    __syncthreads();

    bf16x8 a[2], b[8];
#pragma unroll
    for (int rg = 0; rg < 2; ++rg)
      a[rg] = *reinterpret_cast<const bf16x8*>(
          &As[(wave * 32 + rg * 16 + l15) * APITCH + kh8]);
#pragma unroll
    for (int cg = 0; cg < 8; ++cg)
      b[cg] = *reinterpret_cast<const bf16x8*>(
          &Bs[(cg * 16 + l15) * APITCH + kh8]);
    // Operands swapped: D n = (l>>4)*4 + reg, m = l&15.
#pragma unroll
    for (int rg = 0; rg < 2; ++rg)
#pragma unroll
      for (int cg = 0; cg < 8; ++cg)
        acc[rg][cg] = __builtin_amdgcn_mfma_f32_16x16x32_bf16(
            b[cg], a[rg], acc[rg][cg], 0, 0, 0);
    __syncthreads();

    if (have && valid) {
#pragma unroll
      for (int q = 0; q < 4; ++q) pre[q] = nxt[q];
    }
  }

  // epilogue: lane writes 4 consecutive n as one 8B bf16x4 store
#pragma unroll
  for (int rg = 0; rg < 2; ++rg) {
    const int m = m0 + wave * 32 + rg * 16 + l15;
    if (m < M) {
#pragma unroll
      for (int cg = 0; cg < 8; ++cg) {
        const int nb = n0 + cg * 16 + (lane >> 4) * 4;
        bf16x4 p;
#pragma unroll
        for (int rr = 0; rr < 4; ++rr) p[rr] = (__bf16)acc[rg][cg][rr];
        *reinterpret_cast<bf16x4*>(&S[(size_t)m * D_FEAT + nb]) = p;
      }
    }
  }
}

// ---------------------------------------------------------------------------
// Kernel 3: out[n] = bias + sum val[e]*S[col[e]]   (R5 structure, verbatim)
// Wave per node; half-wave h = edges of parity h; lane = 8 feats (16B).
// ALL batches are full 8-gather batches: index-clamped loads, masked val.
// ---------------------------------------------------------------------------
__global__ __launch_bounds__(256) void spmm_rows(
    const __bf16* __restrict__ S, const int* __restrict__ ptr,
    const int* __restrict__ col, const float* __restrict__ val,
    const float* __restrict__ bias, float* __restrict__ out, int N) {
  const int wave = threadIdx.x >> 6;
  const int lane = threadIdx.x & 63;
  const int n = blockIdx.x * 4 + wave;
  if (n >= N) return;

  const int e0 = ptr[n];
  const int e1 = ptr[n + 1];
  const int hw = lane >> 5;        // 0: even edges, 1: odd edges
  const int f0 = (lane & 31) * 8;  // feature group (8 bf16 = 16B)

  float acc[8] = {};
  const int deg = e1 - e0;
  const int elast = e1 - 1;
  const int nit = (deg + 15) >> 4; // batches of 16 edges (8 per half-wave)

  int e = e0;
  for (int b = 0; b < nit; ++b, e += 16) {
    int cc[8];
    float vv[8];
#pragma unroll
    for (int i = 0; i < 8; ++i) {
      int ee = e + 2 * i + hw;
      const bool ok = ee <= elast;
      ee = ok ? ee : elast;
      cc[i] = col[ee];
      vv[i] = ok ? val[ee] : 0.f;
    }
#pragma unroll
    for (int i = 0; i < 8; ++i) {
      bf16x8 s = *reinterpret_cast<const bf16x8*>(S + (size_t)cc[i] * D_FEAT + f0);
#pragma unroll
      for (int j = 0; j < 8; ++j) acc[j] += vv[i] * (float)s[j];
    }
  }

  // combine half-waves: partner lane is lane ^ 32
#pragma unroll
  for (int j = 0; j < 8; ++j) acc[j] += __shfl(acc[j], lane ^ 32, 64);

  // lane (hw, l5) writes float4 at feature f0 + hw*4 (static acc indexing)
  const int fw = f0 + hw * 4;
  const float4 b = *reinterpret_cast<const float4*>(bias + fw);
  const float r0 = hw ? acc[4] : acc[0];
  const float r1 = hw ? acc[5] : acc[1];
  const float r2 = hw ? acc[6] : acc[2];
  const float r3 = hw ? acc[7] : acc[3];
  f32x4 o;
  o[0] = r0 + b.x; o[1] = r1 + b.y; o[2] = r2 + b.z; o[3] = r3 + b.w;
  __builtin_nontemporal_store(
      o, reinterpret_cast<f32x4*>(out + (size_t)n * D_FEAT + fw));
}

// ---------------------------------------------------------------------------
extern "C" void kernel_launch(void* const* d_in, const int* in_sizes, int n_in,
                              void* d_out, int out_size, void* d_ws, size_t ws_size,
                              hipStream_t stream) {
  const float* x       = (const float*)d_in[0];
  const int*   adj_row = (const int*)d_in[1];
  const int*   adj_col = (const int*)d_in[2];
  const float* adj_val = (const float*)d_in[3];
  const float* weight  = (const float*)d_in[4];
  const float* bias    = (const float*)d_in[5];
  float*       out     = (float*)d_out;

  const int N = in_sizes[0] / D_FEAT;   // 100000
  const int E = in_sizes[1];            // 3200000

  // ws layout: Wt bf16 [256*256] | support bf16 [N*256] | rowptr int [N+1]
  __bf16* Wt      = (__bf16*)d_ws;
  __bf16* support = Wt + 256 * 256;
  int*    rowptr  = (int*)(support + (size_t)N * D_FEAT);

  const int RB = (N + 1 + 255) / 256;   // rowptr blocks
  prep<<<RB + 256, 256, 0, stream>>>(adj_row, E, rowptr, N, weight, Wt, RB);

  {
    dim3 grid(D_FEAT / 128, (N + 127) / 128);
    gemm_mfma<<<grid, 256, 0, stream>>>(x, Wt, support, N);
  }
  {
    const int blocks = (N + 3) / 4;
    spmm_rows<<<blocks, 256, 0, stream>>>(support, rowptr, adj_col, adj_val,
                                          bias, out, N);
  }
}